// Round 8
// baseline (134.202 us; speedup 1.0000x reference)
//
#include <hip/hip_runtime.h>
#include <hip/hip_bf16.h>
#include <cfloat>

// B=32, N=2048 -> BN=65536 rows, D=128, K=1024 codes
#define DIM 128
#define NCODES 1024
#define MTILE 128            // rows per block = 4 waves x 32 rows
#define ROWS_PER_WAVE 32
#define NSUB 2               // 16-row M-subtiles per wave
#define KSTEPS 4             // K=128 / 32
#define CODES_PER_STEP 32    // codes staged to LDS per step
#define NSTEPS (NCODES / CODES_PER_STEP)  // 32
#define PART_HALVES 4096     // one part (hi or lo) per step: 512 chunks * 8 halves = 8 KB
#define STEP_HALVES 8192     // hi + lo per step = 16 KB
#define LOSS_SCALE (12.5f / 8388608.0f)

typedef _Float16 f16x8 __attribute__((ext_vector_type(8)));
typedef float f32x4 __attribute__((ext_vector_type(4)));

// prep: E (fp32) -> f16 hi/lo split written DIRECTLY in MFMA-fragment chunk
// order (chunk = ks*128 + u*64 + quad*16 + m16, 8 halves each), so vq's
// staging copy and ds_read_b128 fragment reads are both lane-consecutive
// (stride-16B = conflict-free; r7's 272B-pitch layout was 8-way conflicted).
// Also enorm = ||E_k||^2; block 0 zeroes loss.
__global__ __launch_bounds__(128) void prep_kernel(const float* __restrict__ E,
                                                   _Float16* __restrict__ Es,
                                                   float* __restrict__ enorm,
                                                   float* __restrict__ loss) {
    const int code = blockIdx.x;
    const int d = threadIdx.x;
    if (code == 0 && d == 0) *loss = 0.f;
    float e = E[code * DIM + d];
    _Float16 h = (_Float16)e;
    _Float16 l = (_Float16)(e - (float)h);
    const int st = code >> 5, u = (code >> 4) & 1, m16 = code & 15;
    const int ks = d >> 5, quad = (d >> 3) & 3, j = d & 7;
    const int chunk = ks * 128 + u * 64 + quad * 16 + m16;
    const size_t base = (size_t)st * STEP_HALVES + (size_t)chunk * 8 + j;
    Es[base] = h;               // hi part: halves [0, 4096) of the step block
    Es[base + PART_HALVES] = l; // lo part: halves [4096, 8192)
    float sq = e * e;
#pragma unroll
    for (int off = 32; off > 0; off >>= 1) sq += __shfl_down(sq, off, 64);
    __shared__ float s2[2];
    if ((d & 63) == 0) s2[d >> 6] = sq;
    __syncthreads();
    if (d == 0) enorm[code] = s2[0] + s2[1];
}

// Fused MFMA dist + argmin + gather + loss, LDS-staged B in fragment order.
// r7 result: LDS staging broke the L1 miss wall (142->64 us) but the padded-
// pitch layout made fragment ds_read_b128 8-way bank-conflicted (4.2M conflict
// cycles). This round: B tiles live in LDS as lane-ordered 16B chunks -> all
// LDS reads/writes are stride-16B conflict-free, global staging reads are one
// contiguous 16KB block per step.
// r3 lesson: no runtime-indexed register arrays. r5 lesson: stay on (256,2).
__global__ __launch_bounds__(256, 2) void vq_kernel(const float* __restrict__ z,
                                                    const _Float16* __restrict__ Es,
                                                    const float* __restrict__ enorm,
                                                    const float* __restrict__ E,
                                                    float* __restrict__ out,
                                                    float* __restrict__ loss) {
    const int t = threadIdx.x;
    const int lane = t & 63;
    const int wave = t >> 6;     // row-wave: rows [wave*32, wave*32+32)
    const int m16 = lane & 15;   // A row within subtile / B,C code col
    const int quad = lane >> 4;  // k-group for A/B; row-group for C

    __shared__ _Float16 s_b[2][STEP_HALVES];  // 2 x 16 KB double buffer
    __shared__ float s_enorm[NCODES];         // 4 KB
    __shared__ float s_znorm[MTILE];
    __shared__ int s_ind[MTILE];
    __shared__ float s_wsum[4];

    for (int i = t; i < NCODES; i += 256) s_enorm[i] = enorm[i];

    // ---- A fragments: wave's 32 rows, K=128, scaled by -2, f16 hi/lo split.
    // A layout (16x16x32): lane holds A[m=lane&15][k=quad*8+j], j=0..7.
    f16x8 Ahi[NSUB][KSTEPS], Alo[NSUB][KSTEPS];
    float znp[NSUB] = {0.f, 0.f};
    const int rowbase = blockIdx.x * MTILE + wave * ROWS_PER_WAVE;
#pragma unroll
    for (int s = 0; s < NSUB; ++s) {
        const int row = rowbase + s * 16 + m16;
        const float* zp = z + (size_t)row * DIM + quad * 8;
#pragma unroll
        for (int ks = 0; ks < KSTEPS; ++ks) {
            float4 v0 = *(const float4*)(zp + ks * 32);
            float4 v1 = *(const float4*)(zp + ks * 32 + 4);
            float zv[8] = {v0.x, v0.y, v0.z, v0.w, v1.x, v1.y, v1.z, v1.w};
#pragma unroll
            for (int j = 0; j < 8; ++j) {
                znp[s] = fmaf(zv[j], zv[j], znp[s]);
                float tt = -2.f * zv[j];
                _Float16 h = (_Float16)tt;
                Ahi[s][ks][j] = h;
                Alo[s][ks][j] = (_Float16)(tt - (float)h);
            }
        }
    }
    // znorm per row -> LDS (consumed after loop; loop barriers order it)
#pragma unroll
    for (int s = 0; s < NSUB; ++s) {
        float v = znp[s];
        v += __shfl_xor(v, 16, 64);
        v += __shfl_xor(v, 32, 64);
        if (quad == 0) s_znorm[wave * ROWS_PER_WAVE + s * 16 + m16] = v;
    }

    float bestv[NSUB][4];
    int besti[NSUB][4];
#pragma unroll
    for (int s = 0; s < NSUB; ++s)
#pragma unroll
        for (int r = 0; r < 4; ++r) {
            bestv[s][r] = FLT_MAX;
            besti[s][r] = 0;
        }

    // Stage step ST's 16 KB tile: 1024 chunks of 16B; thread t copies chunks
    // {t, t+256, t+512, t+768}. Global: contiguous (coalesced); LDS: t*16B
    // consecutive (conflict-free).
#define STAGE(ST, B)                                                 \
    {                                                                \
        const _Float16* src = Es + (size_t)(ST)*STEP_HALVES;         \
        _Pragma("unroll") for (int c = 0; c < 4; ++c) {              \
            const int idx = t + c * 256;                             \
            *(f16x8*)&s_b[B][(size_t)idx * 8] =                      \
                *(const f16x8*)(src + (size_t)idx * 8);              \
        }                                                            \
    }

    STAGE(0, 0)
    __syncthreads();

    int buf = 0;
    for (int st = 0; st < NSTEPS; ++st) {
        if (st + 1 < NSTEPS) STAGE(st + 1, buf ^ 1)  // overlap with compute below
        const _Float16* bh = s_b[buf];
        const _Float16* bl = s_b[buf] + PART_HALVES;
#pragma unroll
        for (int u = 0; u < 2; ++u) {  // two 16-code subgroups
            f16x8 Bh[KSTEPS], Bl[KSTEPS];
#pragma unroll
            for (int ks = 0; ks < KSTEPS; ++ks) {
                const int chunk = ks * 128 + u * 64 + lane;  // lane-consecutive
                Bh[ks] = *(const f16x8*)(bh + (size_t)chunk * 8);
                Bl[ks] = *(const f16x8*)(bl + (size_t)chunk * 8);
            }
            f32x4 acc_hh[NSUB], acc_c[NSUB];
#pragma unroll
            for (int s = 0; s < NSUB; ++s) {
                acc_hh[s] = (f32x4){0.f, 0.f, 0.f, 0.f};
                acc_c[s] = (f32x4){0.f, 0.f, 0.f, 0.f};
            }
#pragma unroll
            for (int ks = 0; ks < KSTEPS; ++ks)
#pragma unroll
                for (int s = 0; s < NSUB; ++s) {
                    acc_c[s] = __builtin_amdgcn_mfma_f32_16x16x32_f16(Ahi[s][ks], Bl[ks], acc_c[s], 0, 0, 0);
                    acc_c[s] = __builtin_amdgcn_mfma_f32_16x16x32_f16(Alo[s][ks], Bh[ks], acc_c[s], 0, 0, 0);
                    acc_hh[s] = __builtin_amdgcn_mfma_f32_16x16x32_f16(Ahi[s][ks], Bh[ks], acc_hh[s], 0, 0, 0);
                }
            const int n = st * CODES_PER_STEP + u * 16 + m16;
            const float e = s_enorm[n];
            // C layout: col = lane&15 (code), row = quad*4 + r
#pragma unroll
            for (int s = 0; s < NSUB; ++s)
#pragma unroll
                for (int r = 0; r < 4; ++r) {
                    float d = (acc_hh[s][r] + acc_c[s][r]) + e;
                    if (d < bestv[s][r]) {  // strict <, ascending n per lane => first-index
                        bestv[s][r] = d;
                        besti[s][r] = n;
                    }
                }
        }
        __syncthreads();  // staged st+1 visible; buf safe to overwrite at st+2
        buf ^= 1;
    }
#undef STAGE

    // ---- in-wave argmin across the 16 m16-lanes (xor butterflies stay in-quad;
    // lexicographic (v,i) merge == global first-index rule)
#pragma unroll
    for (int s = 0; s < NSUB; ++s)
#pragma unroll
        for (int r = 0; r < 4; ++r) {
            float v = bestv[s][r];
            int i = besti[s][r];
#pragma unroll
            for (int m = 1; m <= 8; m <<= 1) {
                float ov = __shfl_xor(v, m, 64);
                int oi = __shfl_xor(i, m, 64);
                if (ov < v || (ov == v && oi < i)) {
                    v = ov;
                    i = oi;
                }
            }
            bestv[s][r] = v;
            besti[s][r] = i;
        }

    float lp = 0.f;
    if (m16 == 0) {  // one winner lane per quad; owns rows quad*4+r (+s*16)
#pragma unroll
        for (int s = 0; s < NSUB; ++s)
#pragma unroll
            for (int r = 0; r < 4; ++r) {
                const int row = wave * ROWS_PER_WAVE + s * 16 + quad * 4 + r;
                s_ind[row] = besti[s][r];
                lp += s_znorm[row] + bestv[s][r];  // ||z-E||^2 = ||z||^2 + dist'
            }
    }
    lp += __shfl_xor(lp, 16, 64);  // lanes {0,16,32,48} hold partials
    lp += __shfl_xor(lp, 32, 64);
    if (lane == 0) s_wsum[wave] = lp;
    __syncthreads();
    if (t == 0)
        atomicAdd(loss, (s_wsum[0] + s_wsum[1] + s_wsum[2] + s_wsum[3]) * LOSS_SCALE);

    // ---- gather-write z_q (STE forward == z_q), float4 coalesced, E is L2-hot
    const float4* E4 = (const float4*)E;
    float4* out4 = (float4*)(out + (size_t)blockIdx.x * (MTILE * DIM));
#pragma unroll
    for (int i = 0; i < (MTILE * DIM) / (256 * 4); ++i) {
        const int f = t + i * 256;  // float4 index within tile
        const int r = f >> 5;       // 32 float4 per row
        const int d = f & 31;
        out4[f] = E4[(size_t)s_ind[r] * 32 + d];
    }
}

extern "C" void kernel_launch(void* const* d_in, const int* in_sizes, int n_in,
                              void* d_out, int out_size, void* d_ws, size_t ws_size,
                              hipStream_t stream) {
    const float* z = (const float*)d_in[0];  // [BN,128] fp32
    const float* E = (const float*)d_in[1];  // [1024,128] fp32
    float* out = (float*)d_out;              // [BN*128] z_q + [1] loss
    float* loss = out + (size_t)(out_size - 1);
    _Float16* Es = (_Float16*)d_ws;                       // 512 KB chunked hi/lo
    float* enorm = (float*)(Es + (size_t)NSTEPS * STEP_HALVES);  // 4 KB
    const int BN = in_sizes[0] / DIM;

    prep_kernel<<<NCODES, 128, 0, stream>>>(E, Es, enorm, loss);
    vq_kernel<<<BN / MTILE, 256, 0, stream>>>(z, Es, enorm, E, out, loss);
}